// Round 7
// baseline (22.397 us; speedup 1.0000x reference)
//
#include <hip/hip_runtime.h>

#define MARGIN 1.0f
// Problem sizes fixed by setup_inputs(): z[8192,100,128] f32, w[100,128], o[8192,100], y[8192]
#define BB  8192
#define CC  100
#define DD  128
#define NBM 256          // main blocks; block NBM does dist -> grid = NBM+1
#define TPB 512          // 8 waves/block

// ws layout (floats):
//   [0,256)   close per-block weighted partials   (atomicExch each launch)
//   [256,512) cls per-block partials              (atomicExch each launch)
//   [512]     loss_dist                           (atomicExch each launch)
//   [513]     arrival counter (int)               (zeroed by 4-byte memset each launch)

__device__ __forceinline__ float wave_reduce_sum(float v) {
    #pragma unroll
    for (int off = 32; off > 0; off >>= 1)
        v += __shfl_down(v, off, 64);
    return v;
}

// valid in thread 0 only
__device__ __forceinline__ float block_reduce_sum(float v, float* s8) {
    int lane = threadIdx.x & 63, wid = threadIdx.x >> 6;
    v = wave_reduce_sum(v);
    if (lane == 0) s8[wid] = v;
    __syncthreads();
    float r = 0.f;
    if (wid == 0) {
        r = (lane < (TPB / 64)) ? s8[lane] : 0.f;
        r = wave_reduce_sum(r);
    }
    __syncthreads();
    return r;
}

__global__ void __launch_bounds__(TPB) fused(
        const float* __restrict__ z, const float* __restrict__ w,
        const float* __restrict__ o, const int* __restrict__ y,
        float* __restrict__ ws, float* __restrict__ out) {
    const int t = threadIdx.x;
    const int blk = blockIdx.x;
    int* ctr = reinterpret_cast<int*>(ws + 2 * NBM + 1);
    __shared__ int s_old;

    if (blk == NBM) {
        // ---- dist: S_i = (sumNorm + C*||w_i||^2 - 2*w_i·colsum) / ((C-1)*D) ----
        __shared__ float s8[TPB / 64];
        __shared__ float s_vec[DD];
        __shared__ float s_p[TPB];
        __shared__ float s_bc;
        int d = t & 127, qq = t >> 7;
        float a = 0.f;
        for (int j = qq; j < CC; j += 4) a += w[j * DD + d];
        s_p[t] = a;
        __syncthreads();
        if (t < 128) s_vec[t] = s_p[t] + s_p[t + 128] + s_p[t + 256] + s_p[t + 384];
        __syncthreads();

        float norm_i = 0.f, dot_i = 0.f;
        if (t < CC) {
            const float4* wp = reinterpret_cast<const float4*>(w + (size_t)t * DD);
            #pragma unroll 8
            for (int k = 0; k < DD / 4; ++k) {
                float4 v = wp[k];
                norm_i += v.x*v.x + v.y*v.y + v.z*v.z + v.w*v.w;
                dot_i  += v.x*s_vec[4*k] + v.y*s_vec[4*k+1]
                        + v.z*s_vec[4*k+2] + v.w*s_vec[4*k+3];
            }
        }
        float sumNorm = block_reduce_sum((t < CC) ? norm_i : 0.f, s8);
        if (t == 0) s_bc = sumNorm;
        __syncthreads();
        sumNorm = s_bc;

        float contrib = 0.f;
        if (t < CC) {
            float S = (sumNorm + (float)CC * norm_i - 2.f * dot_i)
                      / ((float)(CC - 1) * (float)DD);
            contrib = fmaxf(MARGIN - S, 0.f) / (float)CC;
        }
        contrib = block_reduce_sum(contrib, s8);
        if (t == 0) {
            atomicExch(&ws[2 * NBM], contrib);   // device-scope publish
            __threadfence();                     // release
            s_old = atomicAdd(ctr, 1);
        }
    } else {
        // ---- main block: issue all global loads in one latency window ----
        const int lane16 = t & 15;
        const int s = blk * (TPB / 16) + (t >> 4);   // one sample per 16-lane group
        int yb = y[s];

        const float4* zp = reinterpret_cast<const float4*>(z + ((size_t)s * CC + yb) * DD);
        const float4* wp = reinterpret_cast<const float4*>(w + (size_t)yb * DD);
        float4 a0 = zp[lane16];
        float4 a1 = zp[lane16 + 16];
        float4 b0 = wp[lane16];
        float4 b1 = wp[lane16 + 16];

        const float4* o4 = reinterpret_cast<const float4*>(o);
        const int nq = BB * CC / 4;                  // 204800
        const int qi  = blk * TPB + t;               // < 131072
        const int qi2 = qi + NBM * TPB;
        float4 ov0 = o4[qi];
        const bool has2 = (qi2 < nq);
        float4 ov1 = has2 ? o4[qi2] : make_float4(0.f, 0.f, 0.f, 0.f);

        const int4* y4 = reinterpret_cast<const int4*>(y);
        int4 r0 = y4[t];
        int4 r1 = y4[t + 512];
        int4 r2 = y4[t + 1024];
        int4 r3 = y4[t + 1536];

        __shared__ int hist[128];
        if (t < 128) hist[t] = 0;
        __syncthreads();
        atomicAdd(&hist[r0.x], 1); atomicAdd(&hist[r0.y], 1);
        atomicAdd(&hist[r0.z], 1); atomicAdd(&hist[r0.w], 1);
        atomicAdd(&hist[r1.x], 1); atomicAdd(&hist[r1.y], 1);
        atomicAdd(&hist[r1.z], 1); atomicAdd(&hist[r1.w], 1);
        atomicAdd(&hist[r2.x], 1); atomicAdd(&hist[r2.y], 1);
        atomicAdd(&hist[r2.z], 1); atomicAdd(&hist[r2.w], 1);
        atomicAdd(&hist[r3.x], 1); atomicAdd(&hist[r3.y], 1);
        atomicAdd(&hist[r3.z], 1); atomicAdd(&hist[r3.w], 1);
        __syncthreads();

        const int perRow = CC / 4;                   // 25
        float clsAcc;
        {
            int b  = qi / perRow;
            int c0 = (qi - b * perRow) * 4;
            int yv = y[b];
            float e0 = ov0.x - ((c0 + 0 == yv) ? 1.f : 0.f);
            float e1 = ov0.y - ((c0 + 1 == yv) ? 1.f : 0.f);
            float e2 = ov0.z - ((c0 + 2 == yv) ? 1.f : 0.f);
            float e3 = ov0.w - ((c0 + 3 == yv) ? 1.f : 0.f);
            clsAcc = e0*e0 + e1*e1 + e2*e2 + e3*e3;
        }
        if (has2) {
            int b  = qi2 / perRow;
            int c0 = (qi2 - b * perRow) * 4;
            int yv = y[b];
            float e0 = ov1.x - ((c0 + 0 == yv) ? 1.f : 0.f);
            float e1 = ov1.y - ((c0 + 1 == yv) ? 1.f : 0.f);
            float e2 = ov1.z - ((c0 + 2 == yv) ? 1.f : 0.f);
            float e3 = ov1.w - ((c0 + 3 == yv) ? 1.f : 0.f);
            clsAcc += e0*e0 + e1*e1 + e2*e2 + e3*e3;
        }

        float e0 = a0.x-b0.x, e1 = a0.y-b0.y, e2 = a0.z-b0.z, e3 = a0.w-b0.w;
        float f0 = a1.x-b1.x, f1 = a1.y-b1.y, f2 = a1.z-b1.z, f3 = a1.w-b1.w;
        float v = e0*e0 + e1*e1 + e2*e2 + e3*e3
                + f0*f0 + f1*f1 + f2*f2 + f3*f3;
        v += __shfl_xor(v, 1, 64);
        v += __shfl_xor(v, 2, 64);
        v += __shfl_xor(v, 4, 64);
        v += __shfl_xor(v, 8, 64);
        float closeAcc = 0.f;
        if (lane16 == 0)
            closeAcc = v / ((float)hist[yb] * (float)DD);

        const int lane = t & 63, wid = t >> 6;
        float v0 = closeAcc, v1 = clsAcc;
        #pragma unroll
        for (int off = 32; off > 0; off >>= 1) {
            v0 += __shfl_down(v0, off, 64);
            v1 += __shfl_down(v1, off, 64);
        }
        __shared__ float sc[TPB / 64], sk[TPB / 64];
        if (lane == 0) { sc[wid] = v0; sk[wid] = v1; }
        __syncthreads();
        if (t == 0) {
            float c = 0.f, k = 0.f;
            #pragma unroll
            for (int i = 0; i < TPB / 64; ++i) { c += sc[i]; k += sk[i]; }
            atomicExch(&ws[blk], c);             // device-scope publish
            atomicExch(&ws[NBM + blk], k);
            __threadfence();                     // release
            s_old = atomicAdd(ctr, 1);
        }
    }

    __syncthreads();
    // last-arriving block (old == NBM, i.e. all NBM+1 published) does the combine
    if (s_old == NBM && t < 64) {
        __threadfence();                         // acquire
        float c = 0.f, k = 0.f;
        #pragma unroll
        for (int i = 0; i < NBM / 64; ++i) {
            c += atomicAdd(&ws[i * 64 + t], 0.f);          // device-scope read
            k += atomicAdd(&ws[NBM + i * 64 + t], 0.f);
        }
        #pragma unroll
        for (int off = 32; off > 0; off >>= 1) {
            c += __shfl_down(c, off, 64);
            k += __shfl_down(k, off, 64);
        }
        if (t == 0) {
            float cls  = k / ((float)BB * (float)CC);
            float dist = atomicAdd(&ws[2 * NBM], 0.f);
            out[0] = cls + c + dist;
            out[1] = cls;
            out[2] = c;
            out[3] = dist;
        }
    }
}

extern "C" void kernel_launch(void* const* d_in, const int* in_sizes, int n_in,
                              void* d_out, int out_size, void* d_ws, size_t ws_size,
                              hipStream_t stream) {
    const float* z = (const float*)d_in[0];
    const float* w = (const float*)d_in[1];
    const float* o = (const float*)d_in[2];
    const int*   y = (const int*)d_in[3];
    float* out = (float*)d_out;
    float* ws  = (float*)d_ws;

    // zero the arrival counter (ws[513], byte offset 2052) — graph-legal async memset
    hipMemsetAsync((char*)d_ws + (2 * NBM + 1) * sizeof(float), 0, sizeof(int), stream);
    fused<<<NBM + 1, TPB, 0, stream>>>(z, w, o, y, ws, out);
}

// Round 8
// 13.607 us; speedup vs baseline: 1.6460x; 1.6460x over previous
//
#include <hip/hip_runtime.h>

#define MARGIN 1.0f
// Problem sizes are fixed by setup_inputs(): z[8192,100,128] f32, w[100,128], o[8192,100], y[8192]
#define BB  8192
#define CC  100
#define DD  128
#define NBM 256          // main blocks; block NBM does dist -> grid = NBM+1
#define TPB 512          // 8 waves/block

__device__ __forceinline__ float wave_reduce_sum(float v) {
    #pragma unroll
    for (int off = 32; off > 0; off >>= 1)
        v += __shfl_down(v, off, 64);
    return v;
}

// valid in thread 0 only; safe to call repeatedly
__device__ __forceinline__ float block_reduce_sum(float v, float* s8) {
    int lane = threadIdx.x & 63, wid = threadIdx.x >> 6;
    v = wave_reduce_sum(v);
    if (lane == 0) s8[wid] = v;
    __syncthreads();
    float r = 0.f;
    if (wid == 0) {
        r = (lane < (TPB / 64)) ? s8[lane] : 0.f;
        r = wave_reduce_sum(r);
    }
    __syncthreads();
    return r;
}

// ws layout (floats), every cell overwritten each launch (poison-safe, no zeroing):
//   ws[blk]        blk<NBM : close per-block weighted partial
//   ws[NBM+blk]    blk<NBM : cls per-block partial
//   ws[2*NBM]              : loss_dist
__global__ void __launch_bounds__(TPB) k1_main(
        const float* __restrict__ z, const float* __restrict__ w,
        const float* __restrict__ o, const int* __restrict__ y,
        float* __restrict__ ws) {
    const int t = threadIdx.x;
    const int blk = blockIdx.x;

    if (blk == NBM) {
        // ---- dist: S_i = (sumNorm + C*||w_i||^2 - 2*w_i·colsum) / ((C-1)*D) ----
        __shared__ float s8[TPB / 64];
        __shared__ float s_vec[DD];    // column sums
        __shared__ float s_p[TPB];
        __shared__ float s_bc;
        int d = t & 127, qq = t >> 7;          // 4 row-stripes
        float a = 0.f;
        for (int j = qq; j < CC; j += 4) a += w[j * DD + d];
        s_p[t] = a;
        __syncthreads();
        if (t < 128) s_vec[t] = s_p[t] + s_p[t + 128] + s_p[t + 256] + s_p[t + 384];
        __syncthreads();

        float norm_i = 0.f, dot_i = 0.f;
        if (t < CC) {
            const float4* wp = reinterpret_cast<const float4*>(w + (size_t)t * DD);
            #pragma unroll 8
            for (int k = 0; k < DD / 4; ++k) {
                float4 v = wp[k];
                norm_i += v.x*v.x + v.y*v.y + v.z*v.z + v.w*v.w;
                dot_i  += v.x*s_vec[4*k] + v.y*s_vec[4*k+1]
                        + v.z*s_vec[4*k+2] + v.w*s_vec[4*k+3];
            }
        }
        float sumNorm = block_reduce_sum((t < CC) ? norm_i : 0.f, s8);
        if (t == 0) s_bc = sumNorm;
        __syncthreads();
        sumNorm = s_bc;

        float contrib = 0.f;
        if (t < CC) {
            float S = (sumNorm + (float)CC * norm_i - 2.f * dot_i)
                      / ((float)(CC - 1) * (float)DD);
            contrib = fmaxf(MARGIN - S, 0.f) / (float)CC;
        }
        contrib = block_reduce_sum(contrib, s8);
        if (t == 0) ws[2 * NBM] = contrib;
        return;
    }

    // =========== main block: issue ALL global loads in one latency window ===========
    const int lane16 = t & 15;
    const int s = blk * (TPB / 16) + (t >> 4);       // one sample per 16-lane group
    int yb = y[s];                                    // broadcast within group

    // close gather (depends on yb)
    const float4* zp = reinterpret_cast<const float4*>(z + ((size_t)s * CC + yb) * DD);
    const float4* wp = reinterpret_cast<const float4*>(w + (size_t)yb * DD);
    float4 a0 = zp[lane16];
    float4 a1 = zp[lane16 + 16];
    float4 b0 = wp[lane16];
    float4 b1 = wp[lane16 + 16];

    // cls prefetch: 1-2 float4 of o per thread
    const float4* o4 = reinterpret_cast<const float4*>(o);
    const int nq = BB * CC / 4;                       // 204800
    const int qi  = blk * TPB + t;                    // < 131072 < nq
    const int qi2 = qi + NBM * TPB;
    float4 ov0 = o4[qi];
    const bool has2 = (qi2 < nq);
    float4 ov1 = has2 ? o4[qi2] : make_float4(0.f, 0.f, 0.f, 0.f);

    // y-histogram slice into registers (16 labels/thread, coalesced int4)
    const int4* y4 = reinterpret_cast<const int4*>(y);
    int4 r0 = y4[t];
    int4 r1 = y4[t + 512];
    int4 r2 = y4[t + 1024];
    int4 r3 = y4[t + 1536];

    // ---- LDS histogram (overlaps the in-flight global loads) ----
    __shared__ int hist[128];
    if (t < 128) hist[t] = 0;
    __syncthreads();
    atomicAdd(&hist[r0.x], 1); atomicAdd(&hist[r0.y], 1);
    atomicAdd(&hist[r0.z], 1); atomicAdd(&hist[r0.w], 1);
    atomicAdd(&hist[r1.x], 1); atomicAdd(&hist[r1.y], 1);
    atomicAdd(&hist[r1.z], 1); atomicAdd(&hist[r1.w], 1);
    atomicAdd(&hist[r2.x], 1); atomicAdd(&hist[r2.y], 1);
    atomicAdd(&hist[r2.z], 1); atomicAdd(&hist[r2.w], 1);
    atomicAdd(&hist[r3.x], 1); atomicAdd(&hist[r3.y], 1);
    atomicAdd(&hist[r3.z], 1); atomicAdd(&hist[r3.w], 1);
    __syncthreads();

    // ---- cls consume ----
    const int perRow = CC / 4;                        // 25, compile-time constant
    float clsAcc;
    {
        int b  = qi / perRow;
        int c0 = (qi - b * perRow) * 4;
        int yv = y[b];                                // L1-hot
        float e0 = ov0.x - ((c0 + 0 == yv) ? 1.f : 0.f);
        float e1 = ov0.y - ((c0 + 1 == yv) ? 1.f : 0.f);
        float e2 = ov0.z - ((c0 + 2 == yv) ? 1.f : 0.f);
        float e3 = ov0.w - ((c0 + 3 == yv) ? 1.f : 0.f);
        clsAcc = e0*e0 + e1*e1 + e2*e2 + e3*e3;
    }
    if (has2) {
        int b  = qi2 / perRow;
        int c0 = (qi2 - b * perRow) * 4;
        int yv = y[b];
        float e0 = ov1.x - ((c0 + 0 == yv) ? 1.f : 0.f);
        float e1 = ov1.y - ((c0 + 1 == yv) ? 1.f : 0.f);
        float e2 = ov1.z - ((c0 + 2 == yv) ? 1.f : 0.f);
        float e3 = ov1.w - ((c0 + 3 == yv) ? 1.f : 0.f);
        clsAcc += e0*e0 + e1*e1 + e2*e2 + e3*e3;
    }

    // ---- close consume ----
    float e0 = a0.x-b0.x, e1 = a0.y-b0.y, e2 = a0.z-b0.z, e3 = a0.w-b0.w;
    float f0 = a1.x-b1.x, f1 = a1.y-b1.y, f2 = a1.z-b1.z, f3 = a1.w-b1.w;
    float v = e0*e0 + e1*e1 + e2*e2 + e3*e3
            + f0*f0 + f1*f1 + f2*f2 + f3*f3;
    v += __shfl_xor(v, 1, 64);
    v += __shfl_xor(v, 2, 64);
    v += __shfl_xor(v, 4, 64);
    v += __shfl_xor(v, 8, 64);
    float closeAcc = 0.f;
    if (lane16 == 0)
        closeAcc = v / ((float)hist[yb] * (float)DD);

    // ---- combined block reduction (one LDS round) ----
    const int lane = t & 63, wid = t >> 6;
    float v0 = closeAcc, v1 = clsAcc;
    #pragma unroll
    for (int off = 32; off > 0; off >>= 1) {
        v0 += __shfl_down(v0, off, 64);
        v1 += __shfl_down(v1, off, 64);
    }
    __shared__ float sc[TPB / 64], sk[TPB / 64];
    if (lane == 0) { sc[wid] = v0; sk[wid] = v1; }
    __syncthreads();
    if (t == 0) {
        float c = 0.f, k = 0.f;
        #pragma unroll
        for (int i = 0; i < TPB / 64; ++i) { c += sc[i]; k += sk[i]; }
        ws[blk] = c;
        ws[NBM + blk] = k;
    }
}

// K2: one wave — reads 513 floats, combines, writes out. No LDS, no barrier.
__global__ void __launch_bounds__(64) k2_final(const float* __restrict__ ws,
                                               float* __restrict__ out) {
    int lane = threadIdx.x;
    const float4* p = reinterpret_cast<const float4*>(ws);
    float4 a = p[lane];          // close partials [0,256)
    float4 b = p[64 + lane];     // cls partials [256,512)
    float c = a.x + a.y + a.z + a.w;
    float k = b.x + b.y + b.z + b.w;
    #pragma unroll
    for (int off = 32; off > 0; off >>= 1) {
        c += __shfl_down(c, off, 64);
        k += __shfl_down(k, off, 64);
    }
    if (lane == 0) {
        float cls  = k / ((float)BB * (float)CC);
        float dist = ws[2 * NBM];
        out[0] = cls + c + dist;
        out[1] = cls;
        out[2] = c;
        out[3] = dist;
    }
}

extern "C" void kernel_launch(void* const* d_in, const int* in_sizes, int n_in,
                              void* d_out, int out_size, void* d_ws, size_t ws_size,
                              hipStream_t stream) {
    const float* z = (const float*)d_in[0];
    const float* w = (const float*)d_in[1];
    const float* o = (const float*)d_in[2];
    const int*   y = (const int*)d_in[3];
    float* out = (float*)d_out;
    float* ws  = (float*)d_ws;

    k1_main<<<NBM + 1, TPB, 0, stream>>>(z, w, o, y, ws);
    k2_final<<<1, 64, 0, stream>>>(ws, out);
}